// Round 4
// baseline (172.461 us; speedup 1.0000x reference)
//
#include <hip/hip_runtime.h>
#include <hip/hip_fp16.h>

// W8X8Linear: per-row int8 quant (x and w), int8 GEMM via MFMA, dequant+bias.
// M=B*S=32768, N=1024, K=1024 (derived from in_sizes at launch).
//
// Exact-replication notes:
//  - jnp.round == round-half-even == rintf (v_rndne_f32)
//  - scale computed as 127.0f/max (fp32 div) then fp32 mul, like the reference
//  - int32 accumulation == reference's fp32 einsum (|acc| < 2^24, exact)
//  - dequant: fp32 div by 16129, fp16 RN cast, fp32 * (xmax*wmax) + bias
//
// R1: dbuf(drained) + XCD-chunked swizzle (FETCH 130->33 MB). 110->92 us.
// R2: 3-buffer counted-vmcnt pipeline: NULL (93 us). Lockstep barrier
//     structure + low residency is the limiter, not stage latency.
// R3: NO-LDS register GEMM. K=1024 B/row is tiny and both quantized operands
//     are L2-resident (A-slice 4MB/XCD + B 1MB). Each wave = independent
//     64x64 tile, fragments loaded straight from L2 (global_load_dwordx4,
//     64B-contiguous per row), 16 MFMA per K-step, ZERO barriers. Waves
//     overlap freely; compiler pipelines without barrier fences.

typedef int i32x4 __attribute__((ext_vector_type(4)));

// ---------------- quantize: one block per row, K=1024, 256 threads ----------
__global__ __launch_bounds__(256) void quant_rows_kernel(
    const float* __restrict__ in, signed char* __restrict__ q,
    float* __restrict__ rowmax, int K) {
  const int row = blockIdx.x;
  const int t = threadIdx.x;
  const size_t base = (size_t)row * K;
  float4 v = reinterpret_cast<const float4*>(in + base)[t];
  float a = fmaxf(fmaxf(fabsf(v.x), fabsf(v.y)), fmaxf(fabsf(v.z), fabsf(v.w)));
#pragma unroll
  for (int off = 32; off > 0; off >>= 1) a = fmaxf(a, __shfl_xor(a, off, 64));
  __shared__ float smax[4];
  if ((t & 63) == 0) smax[t >> 6] = a;
  __syncthreads();
  float m = fmaxf(fmaxf(smax[0], smax[1]), fmaxf(smax[2], smax[3]));
  float s = 127.0f / m;  // fp32 divide, same as reference
  char4 qq;
  qq.x = (signed char)(int)rintf(v.x * s);
  qq.y = (signed char)(int)rintf(v.y * s);
  qq.z = (signed char)(int)rintf(v.z * s);
  qq.w = (signed char)(int)rintf(v.w * s);
  reinterpret_cast<char4*>(q + base)[t] = qq;
  if (t == 0) rowmax[row] = m;
}

// ------------- int8 GEMM: 4 waves x independent 64x64 tiles, no LDS ---------
__global__ __launch_bounds__(256) void w8x8_gemm_kernel(
    const signed char* __restrict__ Aq, const signed char* __restrict__ Bq,
    const float* __restrict__ Amax, const float* __restrict__ Bmax,
    const float* __restrict__ bias, float* __restrict__ out,
    int M, int N, int K, int cpx) {
  const int t = threadIdx.x;
  const int lane = t & 63;
  const int wave = t >> 6;

  // XCD-chunked swizzle: each XCD gets 32 consecutive bm x all bn
  // -> per-XCD A working set 4 MB (one L2), B 1 MB.
  const int nbn = N / 128;
  const int bid = blockIdx.x;
  const int tile = (bid & 7) * cpx + (bid >> 3);
  const int bm = tile / nbn, bn = tile % nbn;

  // wave (0..3) -> 2x2 arrangement of 64x64 tiles within the 128x128 block
  const int row0 = bm * 128 + (wave >> 1) * 64;
  const int col0 = bn * 128 + (wave & 1) * 64;
  const int fr = lane & 15;  // fragment row-within-16
  const int fq = lane >> 4;  // fragment k-chunk (16B units)

  // MFMA i8 16x16x64 fragment: lane holds 16 consecutive i8 of its row at
  // k-offset fq*16. Per load instruction the wave touches 16 rows x 64
  // contiguous bytes -> L2-friendly.
  const signed char* pa = Aq + (size_t)(row0 + fr) * K + fq * 16;
  const signed char* pb = Bq + (size_t)(col0 + fr) * K + fq * 16;
  const size_t rstride16 = (size_t)16 * K;  // 16 rows

  i32x4 acc[4][4];
#pragma unroll
  for (int m = 0; m < 4; ++m)
#pragma unroll
    for (int n = 0; n < 4; ++n) acc[m][n] = (i32x4){0, 0, 0, 0};

#pragma unroll 2
  for (int kt = 0; kt < K; kt += 64) {
    i32x4 a[4], b[4];
#pragma unroll
    for (int m = 0; m < 4; ++m)
      a[m] = *reinterpret_cast<const i32x4*>(pa + m * rstride16 + kt);
#pragma unroll
    for (int n = 0; n < 4; ++n)
      b[n] = *reinterpret_cast<const i32x4*>(pb + n * rstride16 + kt);
#pragma unroll
    for (int m = 0; m < 4; ++m)
#pragma unroll
      for (int n = 0; n < 4; ++n)
        acc[m][n] = __builtin_amdgcn_mfma_i32_16x16x64_i8(a[m], b[n],
                                                          acc[m][n], 0, 0, 0);
  }

  // Epilogue: C/D layout col = lane&15, row = (lane>>4)*4 + reg
#pragma unroll
  for (int n = 0; n < 4; ++n) {
    int col = col0 + n * 16 + fr;
    float wm = Bmax[col];
    float bs = bias[col];
#pragma unroll
    for (int m = 0; m < 4; ++m) {
      int rowq = row0 + m * 16 + fq * 4;
#pragma unroll
      for (int r = 0; r < 4; ++r) {
        int row = rowq + r;
        float xm = Amax[row];
        float v = (float)acc[m][n][r] / 16129.0f;     // fp32 div like reference
        float h = __half2float(__float2half_rn(v));   // fp16 rounding step
        out[(size_t)row * N + col] = h * (xm * wm) + bs;
      }
    }
  }
}

extern "C" void kernel_launch(void* const* d_in, const int* in_sizes, int n_in,
                              void* d_out, int out_size, void* d_ws, size_t ws_size,
                              hipStream_t stream) {
  const float* x = (const float*)d_in[0];     // [B,S,K] fp32
  const float* w = (const float*)d_in[1];     // [N,K] fp32
  const float* bias = (const float*)d_in[2];  // [N] fp32
  float* out = (float*)d_out;                 // [B,S,N] fp32

  const int N = in_sizes[2];
  const int K = in_sizes[1] / N;   // 1024
  const int M = in_sizes[0] / K;   // 32768

  // workspace layout: x_q | w_q | x_max | w_max  (~34.7 MB total)
  signed char* xq = (signed char*)d_ws;
  signed char* wq = xq + (size_t)M * K;
  float* xmax = (float*)(wq + (size_t)N * K);
  float* wmax = xmax + M;

  quant_rows_kernel<<<M, 256, 0, stream>>>(x, xq, xmax, K);
  quant_rows_kernel<<<N, 256, 0, stream>>>(w, wq, wmax, K);

  const int nwg = (M / 128) * (N / 128);  // 2048, divisible by 8
  const int cpx = nwg / 8;
  w8x8_gemm_kernel<<<nwg, 256, 0, stream>>>(xq, wq, xmax, wmax, bias, out,
                                            M, N, K, cpx);
}

// Round 5
// 107.754 us; speedup vs baseline: 1.6005x; 1.6005x over previous
//
#include <hip/hip_runtime.h>
#include <hip/hip_fp16.h>

// W8X8Linear: per-row int8 quant (x and w), int8 GEMM via MFMA, dequant+bias.
// M=B*S=32768, N=1024, K=1024 (derived from in_sizes at launch).
//
// Exact-replication notes:
//  - jnp.round == round-half-even == rintf (v_rndne_f32)
//  - scale computed as 127.0f/max (fp32 div) then fp32 mul, like the reference
//  - int32 accumulation == reference's fp32 einsum (|acc| < 2^24, exact)
//  - dequant: fp32 div by 16129, fp16 RN cast, fp32 * (xmax*wmax) + bias
//
// R1: dbuf(drained) + XCD-chunked swizzle (FETCH 130->33 MB). 110->92 us.
// R2: counted-vmcnt on 2-barrier 128^2 structure: NULL (93 us) — regime gate.
// R3: no-LDS register GEMM: REGRESSED (158 us) — fragment loads touch 16
//     discontiguous 64B lines each; TA transaction-bound. Reverted.
// R4: 8-phase-style 256^2 port (i8): 8 waves, per-wave 128x64 out, 2 fine
//     phases per K-tile {ds_read || stage -> barrier -> setprio+16 MFMA ->
//     barrier}, 3 LDS buffers, depth-2 prefetch, counted vmcnt(4) once per
//     K-tile (never 0 in loop).

typedef int i32x4 __attribute__((ext_vector_type(4)));

#define BM 256
#define BN 256
#define BKB 64  // K-bytes (= i8 elems) per K-tile

// ---------------- quantize: one block per row, K=1024, 256 threads ----------
__global__ __launch_bounds__(256) void quant_rows_kernel(
    const float* __restrict__ in, signed char* __restrict__ q,
    float* __restrict__ rowmax, int K) {
  const int row = blockIdx.x;
  const int t = threadIdx.x;
  const size_t base = (size_t)row * K;
  float4 v = reinterpret_cast<const float4*>(in + base)[t];
  float a = fmaxf(fmaxf(fabsf(v.x), fabsf(v.y)), fmaxf(fabsf(v.z), fabsf(v.w)));
#pragma unroll
  for (int off = 32; off > 0; off >>= 1) a = fmaxf(a, __shfl_xor(a, off, 64));
  __shared__ float smax[4];
  if ((t & 63) == 0) smax[t >> 6] = a;
  __syncthreads();
  float m = fmaxf(fmaxf(smax[0], smax[1]), fmaxf(smax[2], smax[3]));
  float s = 127.0f / m;  // fp32 divide, same as reference
  char4 qq;
  qq.x = (signed char)(int)rintf(v.x * s);
  qq.y = (signed char)(int)rintf(v.y * s);
  qq.z = (signed char)(int)rintf(v.z * s);
  qq.w = (signed char)(int)rintf(v.w * s);
  reinterpret_cast<char4*>(q + base)[t] = qq;
  if (t == 0) rowmax[row] = m;
}

// ---------------- int8 GEMM, 256x256 tile, 8 waves (2Mx4N) ------------------
__device__ __forceinline__ void gload_lds16(const void* g, void* l) {
  __builtin_amdgcn_global_load_lds(
      (const __attribute__((address_space(1))) unsigned char*)g,
      (__attribute__((address_space(3))) unsigned char*)l, 16, 0, 0);
}

__global__ __launch_bounds__(512, 2) void w8x8_gemm_kernel(
    const signed char* __restrict__ Aq, const signed char* __restrict__ Bq,
    const float* __restrict__ Amax, const float* __restrict__ Bmax,
    const float* __restrict__ bias, float* __restrict__ out,
    int M, int N, int K, int cpx) {
  // 3 K-tile buffers per operand: 3 * 256*64 = 48 KB each, 96 KB total.
  __shared__ __align__(16) signed char ldsA[3 * BM * BKB];
  __shared__ __align__(16) signed char ldsB[3 * BN * BKB];
  const int t = threadIdx.x;
  const int lane = t & 63;
  const int wave = t >> 6;
  const int wm = wave >> 2;  // 0..1  (M half)
  const int wn = wave & 3;   // 0..3  (N quarter)

  // XCD-chunked swizzle: 512 blocks, 64 per XCD -> per-XCD A slice 4 MB (L2).
  const int nbn = N / BN;  // 4
  const int bid = blockIdx.x;
  const int tile = (bid & 7) * cpx + (bid >> 3);
  const int bm = tile / nbn, bn = tile % nbn;

  const signed char* Abase = Aq + (size_t)bm * BM * K;
  const signed char* Bbase = Bq + (size_t)bn * BN * K;

  // Staging: K-tile = 256 rows x 64 B = 1024 16B-chunks; 512 thr x 2 chunks.
  // LDS dest linear (chunk c at byte c*16); global source pre-swizzled:
  // physical chunk p of row r holds logical chunk p ^ ((r>>1)&3).
  const int rS = t >> 2;                       // row of chunk t (and t+512 is +128)
  const int lcS = (t & 3) ^ ((rS >> 1) & 3);   // same for both chunks
  const size_t gA0 = (size_t)rS * K + lcS * 16;
  const size_t gA1 = gA0 + (size_t)128 * K;
  const int dd0 = t * 16, dd1 = t * 16 + 8192;

  // Fragment reads (swizzled): lane(fr,fq) of frag-row r reads
  // r*64 + (fq ^ ((r>>1)&3))*16 ; (r>>1)&3 == (fr>>1)&3 for our r forms.
  const int fr = lane & 15, fq = lane >> 4;
  const int pc = fq ^ ((fr >> 1) & 3);
  const int aoff0 = (wm * 128 + fr) * BKB + pc * 16;
  const int boff0 = (wn * 64 + fr) * BKB + pc * 16;

  i32x4 acc[8][4];
#pragma unroll
  for (int m = 0; m < 8; ++m)
#pragma unroll
    for (int n = 0; n < 4; ++n) acc[m][n] = (i32x4){0, 0, 0, 0};

#define STAGE_A(bf, kt)                                                     \
  do {                                                                      \
    gload_lds16(Abase + gA0 + (size_t)(kt) * BKB, ldsA + (bf)*16384 + dd0); \
    gload_lds16(Abase + gA1 + (size_t)(kt) * BKB, ldsA + (bf)*16384 + dd1); \
  } while (0)
#define STAGE_B(bf, kt)                                                     \
  do {                                                                      \
    gload_lds16(Bbase + gA0 + (size_t)(kt) * BKB, ldsB + (bf)*16384 + dd0); \
    gload_lds16(Bbase + gA1 + (size_t)(kt) * BKB, ldsB + (bf)*16384 + dd1); \
  } while (0)

  const int NT = K / BKB;  // 16
  // Prologue: stage K-tiles 0,1; wait tile 0 (tile 1 stays in flight).
  STAGE_A(0, 0);
  STAGE_B(0, 0);
  STAGE_A(1, 1);
  STAGE_B(1, 1);
  asm volatile("s_waitcnt vmcnt(4)" ::: "memory");
  __builtin_amdgcn_s_barrier();

  int cb = 0;
  for (int kt = 0; kt < NT; ++kt) {
    const signed char* lA = ldsA + cb * 16384;
    const signed char* lB = ldsB + cb * 16384;
    int sb = cb + 2;
    if (sb >= 3) sb -= 3;
    const bool pf = (kt + 2 < NT);

    // ---- phase 1: A-frags + B n=0,1 ; stage next A ; 16 MFMA ----
    i32x4 a[8], b[4];
#pragma unroll
    for (int m = 0; m < 8; ++m)
      a[m] = *reinterpret_cast<const i32x4*>(lA + aoff0 + m * (16 * BKB));
    b[0] = *reinterpret_cast<const i32x4*>(lB + boff0);
    b[1] = *reinterpret_cast<const i32x4*>(lB + boff0 + 16 * BKB);
    if (pf) STAGE_A(sb, kt + 2);
    __builtin_amdgcn_s_barrier();
    __builtin_amdgcn_s_setprio(1);
#pragma unroll
    for (int m = 0; m < 8; ++m) {
      acc[m][0] =
          __builtin_amdgcn_mfma_i32_16x16x64_i8(a[m], b[0], acc[m][0], 0, 0, 0);
      acc[m][1] =
          __builtin_amdgcn_mfma_i32_16x16x64_i8(a[m], b[1], acc[m][1], 0, 0, 0);
    }
    __builtin_amdgcn_s_setprio(0);
    __builtin_amdgcn_s_barrier();

    // ---- phase 2: B n=2,3 ; stage next B ; 16 MFMA ; counted vmcnt ----
    b[2] = *reinterpret_cast<const i32x4*>(lB + boff0 + 2 * 16 * BKB);
    b[3] = *reinterpret_cast<const i32x4*>(lB + boff0 + 3 * 16 * BKB);
    if (pf) STAGE_B(sb, kt + 2);
    __builtin_amdgcn_s_barrier();
    __builtin_amdgcn_s_setprio(1);
#pragma unroll
    for (int m = 0; m < 8; ++m) {
      acc[m][2] =
          __builtin_amdgcn_mfma_i32_16x16x64_i8(a[m], b[2], acc[m][2], 0, 0, 0);
      acc[m][3] =
          __builtin_amdgcn_mfma_i32_16x16x64_i8(a[m], b[3], acc[m][3], 0, 0, 0);
    }
    __builtin_amdgcn_s_setprio(0);
    // kt+1's 4 loads retired; kt+2's 4 stay in flight ACROSS the barrier.
    if (pf)
      asm volatile("s_waitcnt vmcnt(4)" ::: "memory");
    else
      asm volatile("s_waitcnt vmcnt(0)" ::: "memory");
    __builtin_amdgcn_s_barrier();
    cb = (cb + 1 == 3) ? 0 : cb + 1;
  }
#undef STAGE_A
#undef STAGE_B

  // Epilogue: C/D layout col = lane&15, row = (lane>>4)*4 + reg
  const int row0 = bm * BM + wm * 128;
  const int col0 = bn * BN + wn * 64;
#pragma unroll
  for (int n = 0; n < 4; ++n) {
    int col = col0 + n * 16 + fr;
    float wmx = Bmax[col];
    float bs = bias[col];
#pragma unroll
    for (int m = 0; m < 8; ++m) {
      int rowq = row0 + m * 16 + fq * 4;
#pragma unroll
      for (int r = 0; r < 4; ++r) {
        int row = rowq + r;
        float xm = Amax[row];
        float v = (float)acc[m][n][r] / 16129.0f;    // fp32 div like reference
        float h = __half2float(__float2half_rn(v));  // fp16 rounding step
        out[(size_t)row * N + col] = h * (xm * wmx) + bs;
      }
    }
  }
}

extern "C" void kernel_launch(void* const* d_in, const int* in_sizes, int n_in,
                              void* d_out, int out_size, void* d_ws, size_t ws_size,
                              hipStream_t stream) {
  const float* x = (const float*)d_in[0];     // [B,S,K] fp32
  const float* w = (const float*)d_in[1];     // [N,K] fp32
  const float* bias = (const float*)d_in[2];  // [N] fp32
  float* out = (float*)d_out;                 // [B,S,N] fp32

  const int N = in_sizes[2];
  const int K = in_sizes[1] / N;   // 1024
  const int M = in_sizes[0] / K;   // 32768

  // workspace layout: x_q | w_q | x_max | w_max  (~34.7 MB total)
  signed char* xq = (signed char*)d_ws;
  signed char* wq = xq + (size_t)M * K;
  float* xmax = (float*)(wq + (size_t)N * K);
  float* wmax = xmax + M;

  quant_rows_kernel<<<M, 256, 0, stream>>>(x, xq, xmax, K);
  quant_rows_kernel<<<N, 256, 0, stream>>>(w, wq, wmax, K);

  const int nwg = (M / BM) * (N / BN);  // 512, divisible by 8
  const int cpx = nwg / 8;
  w8x8_gemm_kernel<<<nwg, 512, 0, stream>>>(xq, wq, xmax, wmax, bias, out,
                                            M, N, K, cpx);
}